// Round 1
// baseline (2414.571 us; speedup 1.0000x reference)
//
#include <hip/hip_runtime.h>

// 2-layer GCN, N=100000 nodes, E=1200000 edges, all dims 64, fp32.
//
// Pipeline:
//   1. deg[i]=1 (self loop), atomicAdd over dst, dinv=rsqrt(deg)
//   2. h1 = x @ W1                      (bufA)
//   3. agg1 = scatter(h1[src]*norm)     (bufB, atomics, real edges only)
//   4. h2 = relu(agg1 + h1*dinv^2 + b1) (in-place bufB; self-loop fused here)
//   5. h3 = h2 @ W2                     (bufA)
//   6. agg2 = scatter(h3[src]*norm)     (bufB)
//   7. out = (agg2 + h3*dinv^2 + b2) @ Wl + bl   (fused final)

#define FEAT 64

__global__ void k_deg_init(float* __restrict__ deg, int n) {
    int i = blockIdx.x * blockDim.x + threadIdx.x;
    if (i < n) deg[i] = 1.0f;  // self-loop contributes 1
}

__global__ void k_deg_count(const int* __restrict__ dst, float* __restrict__ deg, int E) {
    int i = blockIdx.x * blockDim.x + threadIdx.x;
    if (i < E) atomicAdd(&deg[dst[i]], 1.0f);
}

__global__ void k_dinv(float* __restrict__ deg, int n) {
    int i = blockIdx.x * blockDim.x + threadIdx.x;
    if (i < n) deg[i] = rsqrtf(deg[i]);  // deg >= 1 always (self-loops)
}

// H[n,64] = X[n,64] @ W[64,64]. Block = 256 threads = 4 rows x 64 cols.
__global__ void k_gemm64(const float* __restrict__ X, const float* __restrict__ W,
                         float* __restrict__ H, int n) {
    __shared__ float Ws[64][65];  // +1 pad
    int tid = threadIdx.x;
    for (int i = tid; i < 64 * 64; i += 256) Ws[i >> 6][i & 63] = W[i];
    __syncthreads();
    int row = blockIdx.x * 4 + (tid >> 6);
    int col = tid & 63;
    if (row >= n) return;
    const float* xr = X + (size_t)row * FEAT;
    float acc = 0.f;
#pragma unroll
    for (int k = 0; k < 64; ++k) acc += xr[k] * Ws[k][col];
    H[(size_t)row * FEAT + col] = acc;
}

// 16 threads per edge, float4 (4 feats) each: coalesced 256B row gather,
// 4 fp32 atomics scatter per thread.
__global__ void k_aggregate(const int* __restrict__ src, const int* __restrict__ dst,
                            const float* __restrict__ dinv,
                            const float* __restrict__ H, float* __restrict__ out, int E) {
    long long t = (long long)blockIdx.x * blockDim.x + threadIdx.x;
    int e = (int)(t >> 4);
    if (e >= E) return;
    int f = (int)(t & 15) << 2;
    int s = src[e], d = dst[e];
    float norm = dinv[s] * dinv[d];
    const float4 hv = *(const float4*)(H + (size_t)s * FEAT + f);
    float* o = out + (size_t)d * FEAT + f;
    atomicAdd(o + 0, hv.x * norm);
    atomicAdd(o + 1, hv.y * norm);
    atomicAdd(o + 2, hv.z * norm);
    atomicAdd(o + 3, hv.w * norm);
}

// agg = relu(agg + H*dinv^2 + b)  — float4 vectorized, fused self-loop.
__global__ void k_epilogue_relu(float4* __restrict__ agg, const float4* __restrict__ H,
                                const float* __restrict__ dinv, const float* __restrict__ b,
                                int n) {
    int t = blockIdx.x * blockDim.x + threadIdx.x;
    if (t >= n * 16) return;
    int row = t >> 4;
    int f4 = t & 15;
    float di = dinv[row];
    float d2 = di * di;
    float4 a = agg[t];
    float4 h = H[t];
    float4 bv = ((const float4*)b)[f4];
    float4 r;
    r.x = fmaxf(a.x + h.x * d2 + bv.x, 0.f);
    r.y = fmaxf(a.y + h.y * d2 + bv.y, 0.f);
    r.z = fmaxf(a.z + h.z * d2 + bv.z, 0.f);
    r.w = fmaxf(a.w + h.w * d2 + bv.w, 0.f);
    agg[t] = r;
}

// out = (agg + H*dinv^2 + b2) @ Wl + bl.  Block = 4 rows x 64 cols.
__global__ void k_final(const float* __restrict__ agg, const float* __restrict__ H,
                        const float* __restrict__ dinv, const float* __restrict__ b2,
                        const float* __restrict__ Wl, const float* __restrict__ bl,
                        float* __restrict__ out, int n) {
    __shared__ float Ws[64][65];
    __shared__ float Ts[4][65];
    int tid = threadIdx.x;
    for (int i = tid; i < 64 * 64; i += 256) Ws[i >> 6][i & 63] = Wl[i];
    int row = blockIdx.x * 4 + (tid >> 6);
    int col = tid & 63;
    float tval = 0.f;
    if (row < n) {
        float di = dinv[row];
        size_t idx = (size_t)row * FEAT + col;
        tval = agg[idx] + H[idx] * di * di + b2[col];
    }
    Ts[tid >> 6][col] = tval;
    __syncthreads();
    if (row >= n) return;
    float acc = bl[col];
#pragma unroll
    for (int k = 0; k < 64; ++k) acc += Ts[tid >> 6][k] * Ws[k][col];
    out[(size_t)row * FEAT + col] = acc;
}

extern "C" void kernel_launch(void* const* d_in, const int* in_sizes, int n_in,
                              void* d_out, int out_size, void* d_ws, size_t ws_size,
                              hipStream_t stream) {
    const float* x  = (const float*)d_in[0];
    const int*   ei = (const int*)d_in[1];   // [2][E] int32
    const float* W1 = (const float*)d_in[2];
    const float* b1 = (const float*)d_in[3];
    const float* W2 = (const float*)d_in[4];
    const float* b2 = (const float*)d_in[5];
    const float* Wl = (const float*)d_in[6];
    const float* bl = (const float*)d_in[7];
    float* out = (float*)d_out;

    const int n = in_sizes[0] / FEAT;   // 100000
    const int E = in_sizes[1] / 2;      // 1200000
    const int* src = ei;
    const int* dst = ei + E;

    // workspace layout
    float* dinv = (float*)d_ws;
    size_t nAl = ((size_t)n + 63) & ~(size_t)63;
    float* bufA = dinv + nAl;                    // h1 / h3
    float* bufB = bufA + (size_t)n * FEAT;       // agg1/h2 / agg2

    const int B = 256;
    dim3 blk(B);

    // degrees
    k_deg_init<<<dim3((n + B - 1) / B), blk, 0, stream>>>(dinv, n);
    k_deg_count<<<dim3((E + B - 1) / B), blk, 0, stream>>>(dst, dinv, E);
    k_dinv<<<dim3((n + B - 1) / B), blk, 0, stream>>>(dinv, n);

    int gemm_blocks = (n + 3) / 4;
    long long aggT = (long long)E * 16;
    int agg_blocks = (int)((aggT + B - 1) / B);
    int epi_blocks = (n * 16 + B - 1) / B;

    // layer 1
    k_gemm64<<<dim3(gemm_blocks), blk, 0, stream>>>(x, W1, bufA, n);
    hipMemsetAsync(bufB, 0, (size_t)n * FEAT * sizeof(float), stream);
    k_aggregate<<<dim3(agg_blocks), blk, 0, stream>>>(src, dst, dinv, bufA, bufB, E);
    k_epilogue_relu<<<dim3(epi_blocks), blk, 0, stream>>>(
        (float4*)bufB, (const float4*)bufA, dinv, b1, n);

    // layer 2
    k_gemm64<<<dim3(gemm_blocks), blk, 0, stream>>>(bufB, W2, bufA, n);
    hipMemsetAsync(bufB, 0, (size_t)n * FEAT * sizeof(float), stream);
    k_aggregate<<<dim3(agg_blocks), blk, 0, stream>>>(src, dst, dinv, bufA, bufB, E);

    // final: epilogue2 + @Wl + bl
    k_final<<<dim3(gemm_blocks), blk, 0, stream>>>(bufB, bufA, dinv, b2, Wl, bl, out, n);
}

// Round 2
// 588.592 us; speedup vs baseline: 4.1023x; 4.1023x over previous
//
#include <hip/hip_runtime.h>

// 2-layer GCN, N=100000, E=1200000, dims 64, fp32.
//
// R2: replace fp32 scatter-atomics (1.2 GB WRITE_SIZE, 1018 us/layer) with a
// CSR gather-reduce. Per call:
//   1. cnt[d] = in-degree (int histogram atomics)
//   2. exclusive prefix scan -> offs[], cursor[]
//   3. scatter src ids into ssrc[] (counting sort by dst)
//   4. dinv[i] = rsqrt(cnt[i]+1)
//   5. h1 = x @ W1
//   6. h2 = relu(csr_agg(h1) + h1*dinv^2 + b1)     [one wave per node, no atomics]
//   7. h3 = h2 @ W2
//   8. out = (csr_agg(h3) + h3*dinv^2 + b2) @ Wl + bl   [fused in one kernel]

#define FEAT 64

__global__ void k_hist(const int* __restrict__ dst, int* __restrict__ cnt, int E) {
    int e = blockIdx.x * blockDim.x + threadIdx.x;
    if (e < E) atomicAdd(&cnt[dst[e]], 1);
}

// block-level exclusive scan, pass 1: per-block Hillis-Steele, emit partials + block sums
__global__ void k_scan1(const int* __restrict__ cnt, int* __restrict__ partial,
                        int* __restrict__ blockSum, int n) {
    __shared__ int s[256];
    int t = threadIdx.x;
    int i = blockIdx.x * 256 + t;
    int v = (i < n) ? cnt[i] : 0;
    s[t] = v;
    __syncthreads();
    for (int off = 1; off < 256; off <<= 1) {
        int x = (t >= off) ? s[t - off] : 0;
        __syncthreads();
        s[t] += x;
        __syncthreads();
    }
    if (i < n) partial[i] = s[t] - v;           // exclusive within block
    if (t == 255) blockSum[blockIdx.x] = s[255];
}

// pass 2: scan the block sums (nb <= 512) in one block, in-place exclusive
__global__ void k_scan2(int* __restrict__ blockSum, int nb) {
    __shared__ int s[512];
    int t = threadIdx.x;
    int v = (t < nb) ? blockSum[t] : 0;
    s[t] = v;
    __syncthreads();
    for (int off = 1; off < 512; off <<= 1) {
        int x = (t >= off) ? s[t - off] : 0;
        __syncthreads();
        s[t] += x;
        __syncthreads();
    }
    if (t < nb) blockSum[t] = s[t] - v;
}

// pass 3: add block offsets, produce offs + cursor copies; offs[n] = E
__global__ void k_scan3(int* __restrict__ offs, const int* __restrict__ blockSum,
                        int* __restrict__ cursor, int n, int E) {
    int i = blockIdx.x * 256 + threadIdx.x;
    if (i < n) {
        int o = offs[i] + blockSum[blockIdx.x];
        offs[i] = o;
        cursor[i] = o;
    }
    if (i == 0) offs[n] = E;
}

__global__ void k_scatter(const int* __restrict__ src, const int* __restrict__ dst,
                          int* __restrict__ cursor, int* __restrict__ ssrc, int E) {
    int e = blockIdx.x * blockDim.x + threadIdx.x;
    if (e < E) {
        int p = atomicAdd(&cursor[dst[e]], 1);
        ssrc[p] = src[e];
    }
}

__global__ void k_dinv(const int* __restrict__ cnt, float* __restrict__ dinv, int n) {
    int i = blockIdx.x * blockDim.x + threadIdx.x;
    if (i < n) dinv[i] = rsqrtf((float)cnt[i] + 1.0f);  // +1 self-loop
}

// H[n,64] = X[n,64] @ W[64,64]. Block = 256 = 4 rows x 64 cols, W staged in LDS.
__global__ void k_gemm64(const float* __restrict__ X, const float* __restrict__ W,
                         float* __restrict__ H, int n) {
    __shared__ float Ws[64][65];
    int tid = threadIdx.x;
    for (int i = tid; i < 64 * 64; i += 256) Ws[i >> 6][i & 63] = W[i];
    __syncthreads();
    int row = blockIdx.x * 4 + (tid >> 6);
    int col = tid & 63;
    if (row >= n) return;
    const float* xr = X + (size_t)row * FEAT;
    float acc = 0.f;
#pragma unroll
    for (int k = 0; k < 64; ++k) acc += xr[k] * Ws[k][col];
    H[(size_t)row * FEAT + col] = acc;
}

// One wave (64 lanes = 64 feats) per node. Gather h[src] rows, accumulate in
// register, fused self-loop + bias + optional relu, single coalesced write.
__global__ void __launch_bounds__(256)
k_agg_csr(const int* __restrict__ offs, const int* __restrict__ ssrc,
          const float* __restrict__ dinv, const float* __restrict__ H,
          const float* __restrict__ bias, float* __restrict__ out, int n, int relu) {
    int node = blockIdx.x * 4 + (threadIdx.x >> 6);
    if (node >= n) return;
    int lane = threadIdx.x & 63;
    int beg = offs[node], end = offs[node + 1];
    float dd = dinv[node];
    float acc = H[(size_t)node * FEAT + lane] * dd * dd;  // self loop
    int j = beg;
    for (; j + 1 < end; j += 2) {
        int s0 = ssrc[j], s1 = ssrc[j + 1];
        float n0 = dinv[s0] * dd, n1 = dinv[s1] * dd;
        acc += H[(size_t)s0 * FEAT + lane] * n0;
        acc += H[(size_t)s1 * FEAT + lane] * n1;
    }
    if (j < end) {
        int s0 = ssrc[j];
        acc += H[(size_t)s0 * FEAT + lane] * (dinv[s0] * dd);
    }
    acc += bias[lane];
    if (relu) acc = fmaxf(acc, 0.f);
    out[(size_t)node * FEAT + lane] = acc;
}

// Layer-2 aggregation fused with final linear: t = agg + self + b2, out = t@Wl + bl.
__global__ void __launch_bounds__(256)
k_agg_final(const int* __restrict__ offs, const int* __restrict__ ssrc,
            const float* __restrict__ dinv, const float* __restrict__ H,
            const float* __restrict__ b2, const float* __restrict__ Wl,
            const float* __restrict__ bl, float* __restrict__ out, int n) {
    __shared__ float Ws[64][65];
    __shared__ float Ts[4][65];
    int tid = threadIdx.x;
    for (int i = tid; i < 64 * 64; i += 256) Ws[i >> 6][i & 63] = Wl[i];
    int node = blockIdx.x * 4 + (tid >> 6);
    int lane = tid & 63;
    float t = 0.f;
    if (node < n) {
        int beg = offs[node], end = offs[node + 1];
        float dd = dinv[node];
        t = H[(size_t)node * FEAT + lane] * dd * dd;
        int j = beg;
        for (; j + 1 < end; j += 2) {
            int s0 = ssrc[j], s1 = ssrc[j + 1];
            float n0 = dinv[s0] * dd, n1 = dinv[s1] * dd;
            t += H[(size_t)s0 * FEAT + lane] * n0;
            t += H[(size_t)s1 * FEAT + lane] * n1;
        }
        if (j < end) {
            int s0 = ssrc[j];
            t += H[(size_t)s0 * FEAT + lane] * (dinv[s0] * dd);
        }
        t += b2[lane];
    }
    Ts[tid >> 6][lane] = t;
    __syncthreads();
    if (node >= n) return;
    float acc = bl[lane];
#pragma unroll
    for (int k = 0; k < 64; ++k) acc += Ts[tid >> 6][k] * Ws[k][lane];
    out[(size_t)node * FEAT + lane] = acc;
}

extern "C" void kernel_launch(void* const* d_in, const int* in_sizes, int n_in,
                              void* d_out, int out_size, void* d_ws, size_t ws_size,
                              hipStream_t stream) {
    const float* x  = (const float*)d_in[0];
    const int*   ei = (const int*)d_in[1];   // [2][E] int32
    const float* W1 = (const float*)d_in[2];
    const float* b1 = (const float*)d_in[3];
    const float* W2 = (const float*)d_in[4];
    const float* b2 = (const float*)d_in[5];
    const float* Wl = (const float*)d_in[6];
    const float* bl = (const float*)d_in[7];
    float* out = (float*)d_out;

    const int n = in_sizes[0] / FEAT;   // 100000
    const int E = in_sizes[1] / 2;      // 1200000
    const int* src = ei;
    const int* dst = ei + E;

    const int B = 256;
    const int nblocks = (n + B - 1) / B;      // 391
    const int eblocks = (E + B - 1) / B;
    const int gemm_blocks = (n + 3) / 4;

    // workspace layout (ints/floats, all 4B)
    char* w = (char*)d_ws;
    int*   cnt      = (int*)w;              w += (size_t)n * 4;
    int*   offs     = (int*)w;              w += ((size_t)n + 1) * 4;
    int*   cursor   = (int*)w;              w += (size_t)n * 4;
    int*   blockSum = (int*)w;              w += 512 * 4;
    int*   ssrc     = (int*)w;              w += (size_t)E * 4;
    float* dinv     = (float*)w;            w += (size_t)n * 4;
    // align to 16B for float4-friendly access
    w = (char*)(((uintptr_t)w + 15) & ~(uintptr_t)15);
    float* bufA     = (float*)w;            w += (size_t)n * FEAT * 4;
    float* bufB     = (float*)w;

    // ---- CSR build (shared by both layers) ----
    hipMemsetAsync(cnt, 0, (size_t)n * 4, stream);
    k_hist<<<dim3(eblocks), dim3(B), 0, stream>>>(dst, cnt, E);
    k_scan1<<<dim3(nblocks), dim3(B), 0, stream>>>(cnt, offs, blockSum, n);
    k_scan2<<<dim3(1), dim3(512), 0, stream>>>(blockSum, nblocks);
    k_scan3<<<dim3(nblocks), dim3(B), 0, stream>>>(offs, blockSum, cursor, n, E);
    k_scatter<<<dim3(eblocks), dim3(B), 0, stream>>>(src, dst, cursor, ssrc, E);
    k_dinv<<<dim3(nblocks), dim3(B), 0, stream>>>(cnt, dinv, n);

    // ---- layer 1 ----
    k_gemm64<<<dim3(gemm_blocks), dim3(B), 0, stream>>>(x, W1, bufA, n);
    k_agg_csr<<<dim3(gemm_blocks), dim3(B), 0, stream>>>(offs, ssrc, dinv, bufA, b1, bufB, n, 1);

    // ---- layer 2 + final linear ----
    k_gemm64<<<dim3(gemm_blocks), dim3(B), 0, stream>>>(bufB, W2, bufA, n);
    k_agg_final<<<dim3(gemm_blocks), dim3(B), 0, stream>>>(offs, ssrc, dinv, bufA, b2, Wl, bl, out, n);
}

// Round 3
// 506.938 us; speedup vs baseline: 4.7630x; 1.1611x over previous
//
#include <hip/hip_runtime.h>

// 2-layer GCN, N=100000, E=1200000, dims 64, fp32 in/out.
//
// R3: bf16 intermediate H tables. R2 showed aggregation is L2-fill-BW bound:
// FETCH 215 MB of 307 MB logical gather on a 25.6 MB fp32 table (70% L2 miss).
// bf16 halves logical bytes (128 B/row) and halves the table (12.8 MB ->
// better per-XCD L2 residency). GEMM also restages X rows via LDS and edge
// loop unrolled x4 for MLP.

#define FEAT 64

__device__ __forceinline__ unsigned short f2bf(float f) {
    unsigned u = __float_as_uint(f);
    unsigned r = (u + 0x7FFFu + ((u >> 16) & 1u)) >> 16;   // RNE
    return (unsigned short)r;
}
__device__ __forceinline__ float bf2f(unsigned short h) {
    return __uint_as_float(((unsigned)h) << 16);
}

__global__ void k_hist(const int* __restrict__ dst, int* __restrict__ cnt, int E) {
    int e = blockIdx.x * blockDim.x + threadIdx.x;
    if (e < E) atomicAdd(&cnt[dst[e]], 1);
}

__global__ void k_scan1(const int* __restrict__ cnt, int* __restrict__ partial,
                        int* __restrict__ blockSum, int n) {
    __shared__ int s[256];
    int t = threadIdx.x;
    int i = blockIdx.x * 256 + t;
    int v = (i < n) ? cnt[i] : 0;
    s[t] = v;
    __syncthreads();
    for (int off = 1; off < 256; off <<= 1) {
        int x = (t >= off) ? s[t - off] : 0;
        __syncthreads();
        s[t] += x;
        __syncthreads();
    }
    if (i < n) partial[i] = s[t] - v;
    if (t == 255) blockSum[blockIdx.x] = s[255];
}

__global__ void k_scan2(int* __restrict__ blockSum, int nb) {
    __shared__ int s[512];
    int t = threadIdx.x;
    int v = (t < nb) ? blockSum[t] : 0;
    s[t] = v;
    __syncthreads();
    for (int off = 1; off < 512; off <<= 1) {
        int x = (t >= off) ? s[t - off] : 0;
        __syncthreads();
        s[t] += x;
        __syncthreads();
    }
    if (t < nb) blockSum[t] = s[t] - v;
}

__global__ void k_scan3(int* __restrict__ offs, const int* __restrict__ blockSum,
                        int* __restrict__ cursor, int n, int E) {
    int i = blockIdx.x * 256 + threadIdx.x;
    if (i < n) {
        int o = offs[i] + blockSum[blockIdx.x];
        offs[i] = o;
        cursor[i] = o;
    }
    if (i == 0) offs[n] = E;
}

__global__ void k_scatter(const int* __restrict__ src, const int* __restrict__ dst,
                          int* __restrict__ cursor, int* __restrict__ ssrc, int E) {
    int e = blockIdx.x * blockDim.x + threadIdx.x;
    if (e < E) {
        int p = atomicAdd(&cursor[dst[e]], 1);
        ssrc[p] = src[e];
    }
}

__global__ void k_dinv(const int* __restrict__ cnt, float* __restrict__ dinv, int n) {
    int i = blockIdx.x * blockDim.x + threadIdx.x;
    if (i < n) dinv[i] = rsqrtf((float)cnt[i] + 1.0f);
}

// H[n,64] = X[n,64] @ W[64,64], H stored bf16. Block = 4 rows x 64 cols.
// X rows staged in LDS (1 global load/thread instead of 64 L1 re-reads).
template <bool IN_BF16>
__global__ void __launch_bounds__(256)
k_gemm64(const void* __restrict__ Xv, const float* __restrict__ W,
         unsigned short* __restrict__ H, int n) {
    __shared__ float Ws[64][65];
    __shared__ float Xs[4][64];
    int tid = threadIdx.x;
    for (int i = tid; i < 64 * 64; i += 256) Ws[i >> 6][i & 63] = W[i];
    int r = tid >> 6, col = tid & 63;
    int row = blockIdx.x * 4 + r;
    float xv = 0.f;
    if (row < n) {
        if (IN_BF16) xv = bf2f(((const unsigned short*)Xv)[(size_t)row * FEAT + col]);
        else         xv = ((const float*)Xv)[(size_t)row * FEAT + col];
    }
    Xs[r][col] = xv;
    __syncthreads();
    if (row >= n) return;
    float acc = 0.f;
#pragma unroll
    for (int k = 0; k < 64; ++k) acc += Xs[r][k] * Ws[k][col];
    H[(size_t)row * FEAT + col] = f2bf(acc);
}

// One wave per node; gather bf16 rows (128 B each), fp32 accumulate,
// fused self-loop + bias + relu, bf16 output (feeds next gemm / gather).
__global__ void __launch_bounds__(256)
k_agg_csr(const int* __restrict__ offs, const int* __restrict__ ssrc,
          const float* __restrict__ dinv, const unsigned short* __restrict__ H,
          const float* __restrict__ bias, unsigned short* __restrict__ out, int n) {
    int node = blockIdx.x * 4 + (threadIdx.x >> 6);
    if (node >= n) return;
    int lane = threadIdx.x & 63;
    int beg = offs[node], end = offs[node + 1];
    float dd = dinv[node];
    float acc = bf2f(H[(size_t)node * FEAT + lane]) * dd * dd;   // self loop
    int j = beg;
    for (; j + 3 < end; j += 4) {
        int s0 = ssrc[j], s1 = ssrc[j + 1], s2 = ssrc[j + 2], s3 = ssrc[j + 3];
        float n0 = dinv[s0] * dd, n1 = dinv[s1] * dd;
        float n2 = dinv[s2] * dd, n3 = dinv[s3] * dd;
        float h0 = bf2f(H[(size_t)s0 * FEAT + lane]);
        float h1 = bf2f(H[(size_t)s1 * FEAT + lane]);
        float h2 = bf2f(H[(size_t)s2 * FEAT + lane]);
        float h3 = bf2f(H[(size_t)s3 * FEAT + lane]);
        acc += h0 * n0 + h1 * n1 + h2 * n2 + h3 * n3;
    }
    for (; j < end; ++j) {
        int s0 = ssrc[j];
        acc += bf2f(H[(size_t)s0 * FEAT + lane]) * (dinv[s0] * dd);
    }
    acc += bias[lane];
    acc = fmaxf(acc, 0.f);
    out[(size_t)node * FEAT + lane] = f2bf(acc);
}

// Layer-2 aggregation fused with final linear: t = agg+self+b2; out = t@Wl+bl (fp32).
__global__ void __launch_bounds__(256)
k_agg_final(const int* __restrict__ offs, const int* __restrict__ ssrc,
            const float* __restrict__ dinv, const unsigned short* __restrict__ H,
            const float* __restrict__ b2, const float* __restrict__ Wl,
            const float* __restrict__ bl, float* __restrict__ out, int n) {
    __shared__ float Ws[64][65];
    __shared__ float Ts[4][65];
    int tid = threadIdx.x;
    for (int i = tid; i < 64 * 64; i += 256) Ws[i >> 6][i & 63] = Wl[i];
    int node = blockIdx.x * 4 + (tid >> 6);
    int lane = tid & 63;
    float t = 0.f;
    if (node < n) {
        int beg = offs[node], end = offs[node + 1];
        float dd = dinv[node];
        t = bf2f(H[(size_t)node * FEAT + lane]) * dd * dd;
        int j = beg;
        for (; j + 3 < end; j += 4) {
            int s0 = ssrc[j], s1 = ssrc[j + 1], s2 = ssrc[j + 2], s3 = ssrc[j + 3];
            float n0 = dinv[s0] * dd, n1 = dinv[s1] * dd;
            float n2 = dinv[s2] * dd, n3 = dinv[s3] * dd;
            float h0 = bf2f(H[(size_t)s0 * FEAT + lane]);
            float h1 = bf2f(H[(size_t)s1 * FEAT + lane]);
            float h2 = bf2f(H[(size_t)s2 * FEAT + lane]);
            float h3 = bf2f(H[(size_t)s3 * FEAT + lane]);
            t += h0 * n0 + h1 * n1 + h2 * n2 + h3 * n3;
        }
        for (; j < end; ++j) {
            int s0 = ssrc[j];
            t += bf2f(H[(size_t)s0 * FEAT + lane]) * (dinv[s0] * dd);
        }
        t += b2[lane];
    }
    Ts[tid >> 6][lane] = t;
    __syncthreads();
    if (node >= n) return;
    float acc = bl[lane];
#pragma unroll
    for (int k = 0; k < 64; ++k) acc += Ts[tid >> 6][k] * Ws[k][lane];
    out[(size_t)node * FEAT + lane] = acc;
}

extern "C" void kernel_launch(void* const* d_in, const int* in_sizes, int n_in,
                              void* d_out, int out_size, void* d_ws, size_t ws_size,
                              hipStream_t stream) {
    const float* x  = (const float*)d_in[0];
    const int*   ei = (const int*)d_in[1];   // [2][E] int32
    const float* W1 = (const float*)d_in[2];
    const float* b1 = (const float*)d_in[3];
    const float* W2 = (const float*)d_in[4];
    const float* b2 = (const float*)d_in[5];
    const float* Wl = (const float*)d_in[6];
    const float* bl = (const float*)d_in[7];
    float* out = (float*)d_out;

    const int n = in_sizes[0] / FEAT;   // 100000
    const int E = in_sizes[1] / 2;      // 1200000
    const int* src = ei;
    const int* dst = ei + E;

    const int B = 256;
    const int nblocks = (n + B - 1) / B;
    const int eblocks = (E + B - 1) / B;
    const int gemm_blocks = (n + 3) / 4;

    char* w = (char*)d_ws;
    int*   cnt      = (int*)w;              w += (size_t)n * 4;
    int*   offs     = (int*)w;              w += ((size_t)n + 1) * 4;
    int*   cursor   = (int*)w;              w += (size_t)n * 4;
    int*   blockSum = (int*)w;              w += 512 * 4;
    int*   ssrc     = (int*)w;              w += (size_t)E * 4;
    float* dinv     = (float*)w;            w += (size_t)n * 4;
    w = (char*)(((uintptr_t)w + 15) & ~(uintptr_t)15);
    unsigned short* bufA = (unsigned short*)w;  w += (size_t)n * FEAT * 2;  // h1 / h3 (bf16)
    unsigned short* bufB = (unsigned short*)w;                              // h2 (bf16)

    // ---- CSR build ----
    hipMemsetAsync(cnt, 0, (size_t)n * 4, stream);
    k_hist<<<dim3(eblocks), dim3(B), 0, stream>>>(dst, cnt, E);
    k_scan1<<<dim3(nblocks), dim3(B), 0, stream>>>(cnt, offs, blockSum, n);
    k_scan2<<<dim3(1), dim3(512), 0, stream>>>(blockSum, nblocks);
    k_scan3<<<dim3(nblocks), dim3(B), 0, stream>>>(offs, blockSum, cursor, n, E);
    k_scatter<<<dim3(eblocks), dim3(B), 0, stream>>>(src, dst, cursor, ssrc, E);
    k_dinv<<<dim3(nblocks), dim3(B), 0, stream>>>(cnt, dinv, n);

    // ---- layer 1 ----
    k_gemm64<false><<<dim3(gemm_blocks), dim3(B), 0, stream>>>(x, W1, bufA, n);
    k_agg_csr<<<dim3(gemm_blocks), dim3(B), 0, stream>>>(offs, ssrc, dinv, bufA, b1, bufB, n);

    // ---- layer 2 + final linear ----
    k_gemm64<true><<<dim3(gemm_blocks), dim3(B), 0, stream>>>(bufB, W2, bufA, n);
    k_agg_final<<<dim3(gemm_blocks), dim3(B), 0, stream>>>(offs, ssrc, dinv, bufA, b2, Wl, bl, out, n);
}